// Round 22
// baseline (771.811 us; speedup 1.0000x reference)
//
#include <hip/hip_runtime.h>
#include <hip/hip_bf16.h>

#define B_ 2
#define N_ 16384
#define M_ 4096
#define EPS_ 1e-5f

typedef float f32x2 __attribute__((ext_vector_type(2)));
typedef float f32x4 __attribute__((ext_vector_type(4)));

__device__ __forceinline__ float b2f(const __hip_bfloat16 v) { return __bfloat162float(v); }

// dual-dtype input load: f32 != 0 -> buffer is float32, else bfloat16
__device__ __forceinline__ float ldin(const void* p, size_t i, int f32) {
    return f32 ? ((const float*)p)[i] : __bfloat162float(((const __hip_bfloat16*)p)[i]);
}
__device__ __forceinline__ void stout(void* o, size_t i, float v, int f32) {
    if (f32) ((float*)o)[i] = v;
    else     ((__hip_bfloat16*)o)[i] = __float2bfloat16(v);
}

// np-exact d2: dot rounded per product, sequential add; d2 = (hn+ln) - 2*dot
__device__ __forceinline__ float d2np(float x, float y, float z, float hn, float4 q) {
    float dot = __fadd_rn(__fadd_rn(__fmul_rn(x, q.x), __fmul_rn(y, q.y)), __fmul_rn(z, q.z));
    return __fsub_rn(__fadd_rn(hn, q.w), __fmul_rn(2.f, dot));
}
__device__ __forceinline__ float norm3np(float x, float y, float z) {
    return __fadd_rn(__fadd_rn(__fmul_rn(x, x), __fmul_rn(y, y)), __fmul_rn(z, z));
}

// ---------------- workspace layout ----------------
#define O_GE_W1 0
#define O_GE_B1 192
#define O_GE_W2 256
#define O_GE_B2 4352
#define O_QW    4416
#define O_QB    8512
#define O_KW    8576
#define O_KB    12672
#define O_SCW   12736
#define O_SCB   13120
#define O_SHW   13184
#define O_SHB   13568
#define O_BDW1  13632
#define O_BDB1  17728
#define O_BDW2  17792
#define O_BDB2  17856
#define O_RPW1  17920
#define O_RPB1  18112
#define O_RPW2  18176
#define O_RPB2  22272
// byte offsets of data regions (≈7.7 MB proven safe since R4):
#define OB_LR    92160
#define OB_Q     223232
#define OB_KT    4417536
#define OB_VT    5466112
#define OB_KIDX  6514688
#define OB_DFLAG 7694336
// R20: pair-interleaved LR copies for packed-f32 kNN phase 1.
#define OB_PA1   7563264
#define OB_PA2   7628800
// transposed weights (float offsets from ws base): WT[i][c] = Wrow[c][i]
#define O_T_GE_W2 1923840
#define O_T_QW    1927936
#define O_T_KW    1932032
#define O_T_BDW1  1936128

// R19: per-wave compacted candidate cap (tau filter passes ~44 of 4096)
#define TMAX 256

// ---------------- prep R27: 16 blocks (proven) ----------------
__global__ __launch_bounds__(256) void prep_kernel(
    const void* xyz_hr,
    const void* ge_w1, const void* ge_b1, const void* ge_g1, const void* ge_be1,
    const void* ge_m1, const void* ge_v1, const void* ge_w2, const void* ge_b2,
    const void* sc_w, const void* sc_b, const void* sh_w, const void* sh_b,
    const void* q_w, const void* q_b, const void* k_w, const void* k_b,
    const void* bd_w1, const void* bd_b1, const void* bd_g, const void* bd_be,
    const void* bd_m, const void* bd_v, const void* bd_w2, const void* bd_b2,
    const void* rp_w1, const void* rp_b1, const void* rp_g, const void* rp_be,
    const void* rp_m, const void* rp_v, const void* rp_w2, const void* rp_b2,
    float* W, int* dflag)
{
    __shared__ int scnt;
    int t = threadIdx.x;
    if (t == 0) scnt = 0;
    __syncthreads();
    if (t < 128) {
        unsigned short u = ((const unsigned short*)xyz_hr)[t];
        int e = (u >> 7) & 0xFF;
        int ok = (e >= 113 && e <= 132) || ((u & 0x7FFF) == 0);
        if (ok) atomicAdd(&scnt, 1);
    }
    __syncthreads();
    const int f32 = (scnt < 110) ? 1 : 0;

    if (blockIdx.x == 0) {
        if (t == 0) *dflag = f32;
        if (t < 64) {
            float s = ldin(ge_g1, t, f32) * rsqrtf(ldin(ge_v1, t, f32) + EPS_);
            for (int d = 0; d < 3; ++d) W[O_GE_W1 + t*3 + d] = s * ldin(ge_w1, t*3 + d, f32);
            W[O_GE_B1 + t] = s * (ldin(ge_b1, t, f32) - ldin(ge_m1, t, f32)) + ldin(ge_be1, t, f32);
            W[O_GE_B2 + t] = ldin(ge_b2, t, f32);
            W[O_QB + t] = ldin(q_b, t, f32);
            W[O_KB + t] = ldin(k_b, t, f32);
            W[O_SCB + t] = ldin(sc_b, t, f32);
            W[O_SHB + t] = ldin(sh_b, t, f32);
            float sb = ldin(bd_g, t, f32) * rsqrtf(ldin(bd_v, t, f32) + EPS_);
            W[O_BDB1 + t] = sb * (ldin(bd_b1, t, f32) - ldin(bd_m, t, f32)) + ldin(bd_be, t, f32);
            W[O_BDW2 + t] = ldin(bd_w2, t, f32);
            float sr = ldin(rp_g, t, f32) * rsqrtf(ldin(rp_v, t, f32) + EPS_);
            for (int d = 0; d < 3; ++d) W[O_RPW1 + t*3 + d] = sr * ldin(rp_w1, t*3 + d, f32);
            W[O_RPB1 + t] = sr * (ldin(rp_b1, t, f32) - ldin(rp_m, t, f32)) + ldin(rp_be, t, f32);
            W[O_RPB2 + t] = ldin(rp_b2, t, f32);
        }
        if (t == 0) W[O_BDB2] = ldin(bd_b2, 0, f32);
        for (int i = t; i < 384; i += 256) {
            W[O_SCW + i] = ldin(sc_w, i, f32);
            W[O_SHW + i] = ldin(sh_w, i, f32);
        }
    }
    int i = blockIdx.x * 256 + t;
    if (i < 4096) {
        int c = i >> 6, r = i & 63;        // row (output ch), col (input ch)
        float w2 = ldin(ge_w2, i, f32);
        float qw = ldin(q_w, i, f32);
        float kw = ldin(k_w, i, f32);
        float sb = ldin(bd_g, c, f32) * rsqrtf(ldin(bd_v, c, f32) + EPS_);
        float bw = sb * ldin(bd_w1, i, f32);
        W[O_GE_W2 + i] = w2;
        W[O_QW + i]    = qw;
        W[O_KW + i]    = kw;
        W[O_RPW2 + i]  = ldin(rp_w2, i, f32);
        W[O_BDW1 + i]  = bw;
        W[O_T_GE_W2 + r*64 + c] = w2;
        W[O_T_QW    + r*64 + c] = qw;
        W[O_T_KW    + r*64 + c] = kw;
        W[O_T_BDW1  + r*64 + c] = bw;
    }
}

// ---------------- lr kernel: one point per WAVE, lane = channel (R20 form) ----------------
__global__ __launch_bounds__(256) void lr_kernel(
    const void* __restrict__ xyz_lr,
    const void* __restrict__ sft,
    const void* __restrict__ val,
    const float* __restrict__ W,
    __hip_bfloat16* __restrict__ Kt, __hip_bfloat16* __restrict__ Vt,
    float4* __restrict__ LR, float* __restrict__ PA1, float* __restrict__ PA2,
    const int* dflag)
{
    const int f32 = *dflag;
    int lane = threadIdx.x & 63;
    int p = blockIdx.x * 4 + (threadIdx.x >> 6);   // 0..8191
    int b = p >> 12, m = p & (M_ - 1);
    size_t base = (size_t)b*3*M_ + m;
    float x = ldin(xyz_lr, base, f32), y = ldin(xyz_lr, base + M_, f32), z = ldin(xyz_lr, base + 2*M_, f32);
    if (lane == 0) {
        float hn = norm3np(x, y, z);
        LR[p] = make_float4(x, y, z, hn);
        int k = m >> 1, o = m & 1;
        float* a1 = PA1 + ((size_t)b*2048 + k)*4;
        float* a2 = PA2 + ((size_t)b*2048 + k)*4;
        a1[o] = x; a1[2+o] = y;
        a2[o] = z; a2[2+o] = hn;
    }

    const float* w1 = W + O_GE_W1 + lane*3;
    float h = fmaxf(fmaf(w1[2], z, fmaf(w1[1], y, fmaf(w1[0], x, W[O_GE_B1 + lane]))), 0.f);
    float g = W[O_GE_B2 + lane];
#pragma unroll
    for (int i = 0; i < 64; ++i) {
        g = fmaf(W[O_T_GE_W2 + i*64 + lane], __shfl(h, i, 64), g);
    }
    float sc = W[O_SCB + lane], sh = W[O_SHB + lane];
    const float* wsc = W + O_SCW + lane*6;
    const float* wsh = W + O_SHW + lane*6;
#pragma unroll
    for (int d = 0; d < 6; ++d) {
        float s6 = ldin(sft, (size_t)b*6*M_ + d*M_ + m, f32);   // wave-uniform
        sc = fmaf(wsc[d], s6, sc); sh = fmaf(wsh[d], s6, sh);
    }
    float mod = fmaf(g, sc + 1.f, sh);
    float k = W[O_KB + lane];
#pragma unroll
    for (int i = 0; i < 64; ++i) {
        k = fmaf(W[O_T_KW + i*64 + lane], __shfl(mod, i, 64), k);
    }
    Kt[(size_t)p*64 + lane] = __float2bfloat16(k);
    Vt[(size_t)p*64 + lane] = __float2bfloat16(ldin(val, (size_t)b*64*M_ + (size_t)lane*M_ + m, f32));
}

// lexicographic (d, i) compare-exchange: keep smaller at position a
#define CE(da, ia, db, ib) { \
    bool sw_ = (db < da) || (db == da && ib < ia); \
    float td_ = da; int ti_ = ia; \
    da = sw_ ? db : da; ia = sw_ ? ib : ia; \
    db = sw_ ? td_ : db; ib = sw_ ? ti_ : ib; }

// insert (d2, m) into the sorted-16 list if it beats the tail (lex order) [proven R10]
__device__ __forceinline__ void topk_insert(float (&bd)[16], int (&bi)[16], float d2, int m) {
    if (d2 < bd[15] || (d2 == bd[15] && m < bi[15])) {
        bd[15] = d2; bi[15] = m;
#pragma unroll
        for (int j = 15; j > 0; --j) CE(bd[j-1], bi[j-1], bd[j], bi[j]);
    }
}

// lex (d2, idx) compare of LDS entry e against (cd, ci)
__device__ __forceinline__ int lesslex(uint2 e, float cd, int ci) {
    float dj = __uint_as_float(e.x);
    int   ij = (int)e.y;
    return (dj < cd || (dj == cd && ij < ci)) ? 1 : 0;
}

// ---------------- hr + kNN + attn fused (R29) ----------------
// R28 fusion WORKED (knnattn 175.7 vs ~194 serial; total 383.9->365.6).
// Extension by the same mechanism: hr's Q[p][c] is produced with lane=channel
// and consumed by attn as qc=Q[p*64+lane] -- SAME wave, SAME lane. Run hr as
// a prologue here: qc never touches memory (deletes the 4MB Q round-trip and
// its bf16 rounding; f32 qc is CLOSER to the JAX reference). lrhr shrinks to
// lr-only. Not R22's thrash mode: hr is a short same-wave prologue, waves
// move through phases ~in lockstep -> W-tables and PA-panel working sets are
// time-separated.
// Pre-committed: total >= 365 -> same-wave phase mixing also thrashes, revert.
__global__ __launch_bounds__(256, 4) void hrknnattn_kernel(
    const void* __restrict__ xyz_hr,
    const float4* __restrict__ LR,
    const f32x4* __restrict__ PA1, const f32x4* __restrict__ PA2,
    const float* __restrict__ W,
    const __hip_bfloat16* __restrict__ Kt,
    const __hip_bfloat16* __restrict__ Vt,
    void* __restrict__ out, const int* dflag)
{
    __shared__ uint2 scand[4 * TMAX];       // 8 KiB: per-wave compacted (d2 bits, idx)
    __shared__ unsigned short skidx[4*16];  // per-wave top-16 (replaces global kidx)
    const int f32 = *dflag;
    int lane = threadIdx.x & 63;
    int wid  = threadIdx.x >> 6;
    int p = blockIdx.x * 4 + wid;                    // 0..32767, one point per wave
    int b = p >> 14, n = p & (N_ - 1);               // b is block-uniform
    size_t base = (size_t)b*3*N_ + n;
    float x = ldin(xyz_hr, base, f32), y = ldin(xyz_hr, base + N_, f32), z = ldin(xyz_hr, base + 2*N_, f32);
    float hn = norm3np(x, y, z);
    const float4* L = LR + b*M_;

    // ---------- hr prologue: geom enc -> qc (kept in REGISTER), bdy head ----------
    float qc;
    {
        const float* w1 = W + O_GE_W1 + lane*3;
        float h = fmaxf(fmaf(w1[2], z, fmaf(w1[1], y, fmaf(w1[0], x, W[O_GE_B1 + lane]))), 0.f);
        float g = W[O_GE_B2 + lane];
#pragma unroll
        for (int i = 0; i < 64; ++i) {
            g = fmaf(W[O_T_GE_W2 + i*64 + lane], __shfl(h, i, 64), g);
        }
        float q = W[O_QB + lane];
#pragma unroll
        for (int i = 0; i < 64; ++i) {
            q = fmaf(W[O_T_QW + i*64 + lane], __shfl(g, i, 64), q);
        }
        qc = q;                                     // f32, no bf16 round-trip
        float hb = W[O_BDB1 + lane];
#pragma unroll
        for (int i = 0; i < 64; ++i) {
            hb = fmaf(W[O_T_BDW1 + i*64 + lane], __shfl(g, i, 64), hb);
        }
        float o = W[O_BDW2 + lane] * fmaxf(hb, 0.f);
#pragma unroll
        for (int sh = 1; sh < 64; sh <<= 1) o += __shfl_xor(o, sh, 64);
        if (lane == 0) {
            o += W[O_BDB2];
            stout(out, (size_t)B_*64*N_ + (size_t)b*N_ + n, 1.f / (1.f + __expf(-o)), f32);
        }
    }

    { // ---------- knn selection (R25 verbatim; exact-FP scope) ----------
#pragma clang fp reassociate(off)
#pragma clang fp contract(off)
    const f32x4* P1 = PA1 + (size_t)b*2048;
    const f32x4* P2 = PA2 + (size_t)b*2048;

    f32x2 d2p[32];
    f32x2 xx = {x, x}, yy = {y, y}, zz = {z, z}, hh = {hn, hn};
    const f32x2 m2 = {-2.f, -2.f};
    const f32x2 inf2 = {3.4e38f, 3.4e38f};
    f32x2 vm0 = inf2, vm1 = inf2;                    // tree-min accums
#pragma unroll
    for (int c = 0; c < 16; ++c) {
        int k0 = lane + (2*c + 0)*64;
        int k1 = lane + (2*c + 1)*64;
        f32x4 a0 = P1[k0];
        f32x4 b0 = P2[k0];
        f32x4 a1 = P1[k1];
        f32x4 b1 = P2[k1];
        {
            f32x2 qx = __builtin_shufflevector(a0, a0, 0, 1);
            f32x2 qy = __builtin_shufflevector(a0, a0, 2, 3);
            f32x2 qz = __builtin_shufflevector(b0, b0, 0, 1);
            f32x2 qw = __builtin_shufflevector(b0, b0, 2, 3);
            f32x2 dot = ((xx*qx) + (yy*qy)) + (zz*qz);
            f32x2 d2  = __builtin_elementwise_fma(m2, dot, hh + qw);
            d2p[2*c + 0] = d2;
            vm0 = __builtin_elementwise_min(vm0, d2);
        }
        {
            f32x2 qx = __builtin_shufflevector(a1, a1, 0, 1);
            f32x2 qy = __builtin_shufflevector(a1, a1, 2, 3);
            f32x2 qz = __builtin_shufflevector(b1, b1, 0, 1);
            f32x2 qw = __builtin_shufflevector(b1, b1, 2, 3);
            f32x2 dot = ((xx*qx) + (yy*qy)) + (zz*qz);
            f32x2 d2  = __builtin_elementwise_fma(m2, dot, hh + qw);
            d2p[2*c + 1] = d2;
            vm1 = __builtin_elementwise_min(vm1, d2);
        }
    }
    f32x2 vm = __builtin_elementwise_min(vm0, vm1);
    float v = fminf(vm.x, vm.y);
    v = fminf(v, __shfl_xor(v, 16, 64));
    v = fminf(v, __shfl_xor(v, 32, 64));
    float tau = v;
#pragma unroll
    for (int st = 1; st <= 8; st <<= 1) tau = fmaxf(tau, __shfl_xor(tau, st, 64));

    int cnt = 0;
#pragma unroll
    for (int j = 0; j < 32; ++j)
        cnt += ((d2p[j].x <= tau) ? 1 : 0) + ((d2p[j].y <= tau) ? 1 : 0);
    int inc = cnt;
#pragma unroll
    for (int st = 1; st < 64; st <<= 1) {
        int o = __shfl_up(inc, st, 64);
        if (lane >= st) inc += o;
    }
    int off = inc - cnt;                 // exclusive prefix = my write base
    int T = __shfl(inc, 63, 64);         // wave total

    if (T > TMAX) {
        // fallback: full lex top-16 scan (never expected; safety net)
        float bd[16]; int bi[16];
#pragma unroll
        for (int j = 0; j < 16; ++j) { bd[j] = 3.4e38f; bi[j] = 0x7fffffff; }
        for (int m = 0; m < M_; ++m) {
            topk_insert(bd, bi, d2np(x, y, z, hn, L[m]), m);
        }
        if (lane == 0) {
#pragma unroll
            for (int j = 0; j < 16; ++j) skidx[wid*16 + j] = (unsigned short)bi[j];
        }
    } else {
        uint2* wc = scand + wid * TMAX;
#pragma unroll
        for (int j = 0; j < 32; ++j) {
            int m0 = 2*lane + 128*j;
            if (d2p[j].x <= tau) { wc[off] = make_uint2(__float_as_uint(d2p[j].x), (unsigned)m0);     off++; }
            if (d2p[j].y <= tau) { wc[off] = make_uint2(__float_as_uint(d2p[j].y), (unsigned)(m0+1)); off++; }
        }
        int Tp = (T + 3) & ~3;
        if (lane < Tp - T) wc[T + lane] = make_uint2(0x7f800000u, 0xffffu);
        asm volatile("s_waitcnt lgkmcnt(0)" ::: "memory");

        for (int t2 = lane; t2 < T; t2 += 64) {        // T<=64 in practice: 1 iter
            uint2 cv = wc[t2];
            float cd = __uint_as_float(cv.x);
            int   ci = (int)cv.y;
            int rank = 0;
            for (int j = 0; j < Tp; j += 4) {          // wave-uniform j -> broadcast
                uint2 e0 = wc[j], e1 = wc[j+1], e2 = wc[j+2], e3 = wc[j+3];
                rank += lesslex(e0, cd, ci) + lesslex(e1, cd, ci)
                      + lesslex(e2, cd, ci) + lesslex(e3, cd, ci);
            }
            if (rank < 16) skidx[wid*16 + rank] = (unsigned short)ci;
        }
    }
    } // ---------- end knn selection ----------
    // same-wave LDS writes -> visible after waitcnt (no cross-wave sharing)
    asm volatile("s_waitcnt lgkmcnt(0)" ::: "memory");

    // ---------- attn phase (R17 body; qc from register, kidx from LDS) ----------
    float fw0 = W[O_RPW1 + lane*3], fw1 = W[O_RPW1 + lane*3 + 1], fw2 = W[O_RPW1 + lane*3 + 2];
    float fb  = W[O_RPB1 + lane];
    float q2 = 0.f;
#pragma unroll
    for (int cc = 0; cc < 64; ++cc) {
        float qb = __shfl(qc, cc, 64);
        q2 = fmaf(W[O_RPW2 + cc*64 + lane], qb, q2);
    }
    int idxv = (int)skidx[wid*16 + (lane & 15)];
    const __hip_bfloat16* Ktb = Kt + (size_t)b*M_*64;
    const __hip_bfloat16* Vtb = Vt + (size_t)b*M_*64;
    float lg[16];
#pragma unroll
    for (int j = 0; j < 16; ++j) {
        int mj = __shfl(idxv, j, 64);
        mj = (mj < M_) ? mj : (M_ - 1);
        float4 pl = L[mj];
        float r0 = x - pl.x, r1 = y - pl.y, r2 = z - pl.z;
        float pe = fmaxf(fmaf(fw2, r2, fmaf(fw1, r1, fmaf(fw0, r0, fb))), 0.f);
        float vv = fmaf(qc, b2f(Ktb[(size_t)mj*64 + lane]), q2 * pe);
#pragma unroll
        for (int sh = 1; sh < 64; sh <<= 1) vv += __shfl_xor(vv, sh, 64);
        lg[j] = vv * 0.125f;
    }
    float mx = lg[0];
#pragma unroll
    for (int j = 1; j < 16; ++j) mx = fmaxf(mx, lg[j]);
    float sum = 0.f;
#pragma unroll
    for (int j = 0; j < 16; ++j) { lg[j] = __expf(lg[j] - mx); sum += lg[j]; }
    float inv = 1.f / sum;
    float o = 0.f;
#pragma unroll
    for (int j = 0; j < 16; ++j) {
        int mj = __shfl(idxv, j, 64);
        mj = (mj < M_) ? mj : (M_ - 1);
        o = fmaf(lg[j] * inv, b2f(Vtb[(size_t)mj*64 + lane]), o);
    }
    stout(out, ((size_t)(b*64 + lane))*N_ + n, o, f32);
}

// ---------------- launch ----------------
extern "C" void kernel_launch(void* const* d_in, const int* in_sizes, int n_in,
                              void* d_out, int out_size, void* d_ws, size_t ws_size,
                              hipStream_t stream) {
    const void* xyz_hr = d_in[0];
    const void* xyz_lr = d_in[1];
    const void* sft    = d_in[2];
    const void* val    = d_in[3];

    char* ws = (char*)d_ws;
    float* W  = (float*)ws;
    float4* LR = (float4*)(ws + OB_LR);
    __hip_bfloat16* Kt = (__hip_bfloat16*)(ws + OB_KT);
    __hip_bfloat16* Vt = (__hip_bfloat16*)(ws + OB_VT);
    float* PA1 = (float*)(ws + OB_PA1);
    float* PA2 = (float*)(ws + OB_PA2);
    int* dflag = (int*)(ws + OB_DFLAG);

    prep_kernel<<<16, 256, 0, stream>>>(
        xyz_hr,
        d_in[4],  d_in[5],  d_in[6],  d_in[7],  d_in[8],  d_in[9],  d_in[10], d_in[11],
        d_in[12], d_in[13], d_in[14], d_in[15], d_in[16], d_in[17], d_in[18], d_in[19],
        d_in[20], d_in[21], d_in[22], d_in[23], d_in[24], d_in[25], d_in[26], d_in[27],
        d_in[28], d_in[29], d_in[30], d_in[31], d_in[32], d_in[33], d_in[34], d_in[35],
        W, dflag);
    lr_kernel<<<2048, 256, 0, stream>>>(xyz_lr, sft, val, W, Kt, Vt, LR, PA1, PA2, dflag);
    hrknnattn_kernel<<<8192, 256, 0, stream>>>(xyz_hr, LR, (const f32x4*)PA1, (const f32x4*)PA2,
                                               W, Kt, Vt, d_out, dflag);
}

// Round 25
// 346.138 us; speedup vs baseline: 2.2298x; 2.2298x over previous
//
#include <hip/hip_runtime.h>
#include <hip/hip_bf16.h>

#define B_ 2
#define N_ 16384
#define M_ 4096
#define EPS_ 1e-5f

typedef float f32x2 __attribute__((ext_vector_type(2)));
typedef float f32x4 __attribute__((ext_vector_type(4)));

__device__ __forceinline__ float b2f(const __hip_bfloat16 v) { return __bfloat162float(v); }

// dual-dtype input load: f32 != 0 -> buffer is float32, else bfloat16
__device__ __forceinline__ float ldin(const void* p, size_t i, int f32) {
    return f32 ? ((const float*)p)[i] : __bfloat162float(((const __hip_bfloat16*)p)[i]);
}
__device__ __forceinline__ void stout(void* o, size_t i, float v, int f32) {
    if (f32) ((float*)o)[i] = v;
    else     ((__hip_bfloat16*)o)[i] = __float2bfloat16(v);
}

// np-exact d2: dot rounded per product, sequential add; d2 = (hn+ln) - 2*dot
__device__ __forceinline__ float d2np(float x, float y, float z, float hn, float4 q) {
    float dot = __fadd_rn(__fadd_rn(__fmul_rn(x, q.x), __fmul_rn(y, q.y)), __fmul_rn(z, q.z));
    return __fsub_rn(__fadd_rn(hn, q.w), __fmul_rn(2.f, dot));
}
__device__ __forceinline__ float norm3np(float x, float y, float z) {
    return __fadd_rn(__fadd_rn(__fmul_rn(x, x), __fmul_rn(y, y)), __fmul_rn(z, z));
}

// ---------------- workspace layout ----------------
#define O_GE_W1 0
#define O_GE_B1 192
#define O_GE_W2 256
#define O_GE_B2 4352
#define O_QW    4416
#define O_QB    8512
#define O_KW    8576
#define O_KB    12672
#define O_SCW   12736
#define O_SCB   13120
#define O_SHW   13184
#define O_SHB   13568
#define O_BDW1  13632
#define O_BDB1  17728
#define O_BDW2  17792
#define O_BDB2  17856
#define O_RPW1  17920
#define O_RPB1  18112
#define O_RPW2  18176
#define O_RPB2  22272
// byte offsets of data regions (≈7.7 MB proven safe since R4):
#define OB_LR    92160
#define OB_Q     223232
#define OB_KT    4417536
#define OB_VT    5466112
#define OB_KIDX  6514688
#define OB_DFLAG 7694336
// R20: pair-interleaved LR copies for packed-f32 kNN phase 1.
#define OB_PA1   7563264
#define OB_PA2   7628800
// transposed weights (float offsets from ws base): WT[i][c] = Wrow[c][i]
#define O_T_GE_W2 1923840
#define O_T_QW    1927936
#define O_T_KW    1932032
#define O_T_BDW1  1936128

// R19: per-wave compacted candidate cap (tau filter passes ~44 of 4096)
#define TMAX 256

// ---------------- prep R27: 16 blocks (proven) ----------------
__global__ __launch_bounds__(256) void prep_kernel(
    const void* xyz_hr,
    const void* ge_w1, const void* ge_b1, const void* ge_g1, const void* ge_be1,
    const void* ge_m1, const void* ge_v1, const void* ge_w2, const void* ge_b2,
    const void* sc_w, const void* sc_b, const void* sh_w, const void* sh_b,
    const void* q_w, const void* q_b, const void* k_w, const void* k_b,
    const void* bd_w1, const void* bd_b1, const void* bd_g, const void* bd_be,
    const void* bd_m, const void* bd_v, const void* bd_w2, const void* bd_b2,
    const void* rp_w1, const void* rp_b1, const void* rp_g, const void* rp_be,
    const void* rp_m, const void* rp_v, const void* rp_w2, const void* rp_b2,
    float* W, int* dflag)
{
    __shared__ int scnt;
    int t = threadIdx.x;
    if (t == 0) scnt = 0;
    __syncthreads();
    if (t < 128) {
        unsigned short u = ((const unsigned short*)xyz_hr)[t];
        int e = (u >> 7) & 0xFF;
        int ok = (e >= 113 && e <= 132) || ((u & 0x7FFF) == 0);
        if (ok) atomicAdd(&scnt, 1);
    }
    __syncthreads();
    const int f32 = (scnt < 110) ? 1 : 0;

    if (blockIdx.x == 0) {
        if (t == 0) *dflag = f32;
        if (t < 64) {
            float s = ldin(ge_g1, t, f32) * rsqrtf(ldin(ge_v1, t, f32) + EPS_);
            for (int d = 0; d < 3; ++d) W[O_GE_W1 + t*3 + d] = s * ldin(ge_w1, t*3 + d, f32);
            W[O_GE_B1 + t] = s * (ldin(ge_b1, t, f32) - ldin(ge_m1, t, f32)) + ldin(ge_be1, t, f32);
            W[O_GE_B2 + t] = ldin(ge_b2, t, f32);
            W[O_QB + t] = ldin(q_b, t, f32);
            W[O_KB + t] = ldin(k_b, t, f32);
            W[O_SCB + t] = ldin(sc_b, t, f32);
            W[O_SHB + t] = ldin(sh_b, t, f32);
            float sb = ldin(bd_g, t, f32) * rsqrtf(ldin(bd_v, t, f32) + EPS_);
            W[O_BDB1 + t] = sb * (ldin(bd_b1, t, f32) - ldin(bd_m, t, f32)) + ldin(bd_be, t, f32);
            W[O_BDW2 + t] = ldin(bd_w2, t, f32);
            float sr = ldin(rp_g, t, f32) * rsqrtf(ldin(rp_v, t, f32) + EPS_);
            for (int d = 0; d < 3; ++d) W[O_RPW1 + t*3 + d] = sr * ldin(rp_w1, t*3 + d, f32);
            W[O_RPB1 + t] = sr * (ldin(rp_b1, t, f32) - ldin(rp_m, t, f32)) + ldin(rp_be, t, f32);
            W[O_RPB2 + t] = ldin(rp_b2, t, f32);
        }
        if (t == 0) W[O_BDB2] = ldin(bd_b2, 0, f32);
        for (int i = t; i < 384; i += 256) {
            W[O_SCW + i] = ldin(sc_w, i, f32);
            W[O_SHW + i] = ldin(sh_w, i, f32);
        }
    }
    int i = blockIdx.x * 256 + t;
    if (i < 4096) {
        int c = i >> 6, r = i & 63;        // row (output ch), col (input ch)
        float w2 = ldin(ge_w2, i, f32);
        float qw = ldin(q_w, i, f32);
        float kw = ldin(k_w, i, f32);
        float sb = ldin(bd_g, c, f32) * rsqrtf(ldin(bd_v, c, f32) + EPS_);
        float bw = sb * ldin(bd_w1, i, f32);
        W[O_GE_W2 + i] = w2;
        W[O_QW + i]    = qw;
        W[O_KW + i]    = kw;
        W[O_RPW2 + i]  = ldin(rp_w2, i, f32);
        W[O_BDW1 + i]  = bw;
        W[O_T_GE_W2 + r*64 + c] = w2;
        W[O_T_QW    + r*64 + c] = qw;
        W[O_T_KW    + r*64 + c] = kw;
        W[O_T_BDW1  + r*64 + c] = bw;
    }
}

// ---------------- lr kernel: one point per WAVE, lane = channel (R20 form) ----------------
__global__ __launch_bounds__(256) void lr_kernel(
    const void* __restrict__ xyz_lr,
    const void* __restrict__ sft,
    const void* __restrict__ val,
    const float* __restrict__ W,
    __hip_bfloat16* __restrict__ Kt, __hip_bfloat16* __restrict__ Vt,
    float4* __restrict__ LR, float* __restrict__ PA1, float* __restrict__ PA2,
    const int* dflag)
{
    const int f32 = *dflag;
    int lane = threadIdx.x & 63;
    int p = blockIdx.x * 4 + (threadIdx.x >> 6);   // 0..8191
    int b = p >> 12, m = p & (M_ - 1);
    size_t base = (size_t)b*3*M_ + m;
    float x = ldin(xyz_lr, base, f32), y = ldin(xyz_lr, base + M_, f32), z = ldin(xyz_lr, base + 2*M_, f32);
    if (lane == 0) {
        float hn = norm3np(x, y, z);
        LR[p] = make_float4(x, y, z, hn);
        int k = m >> 1, o = m & 1;
        float* a1 = PA1 + ((size_t)b*2048 + k)*4;
        float* a2 = PA2 + ((size_t)b*2048 + k)*4;
        a1[o] = x; a1[2+o] = y;
        a2[o] = z; a2[2+o] = hn;
    }

    const float* w1 = W + O_GE_W1 + lane*3;
    float h = fmaxf(fmaf(w1[2], z, fmaf(w1[1], y, fmaf(w1[0], x, W[O_GE_B1 + lane]))), 0.f);
    float g = W[O_GE_B2 + lane];
#pragma unroll
    for (int i = 0; i < 64; ++i) {
        g = fmaf(W[O_T_GE_W2 + i*64 + lane], __shfl(h, i, 64), g);
    }
    float sc = W[O_SCB + lane], sh = W[O_SHB + lane];
    const float* wsc = W + O_SCW + lane*6;
    const float* wsh = W + O_SHW + lane*6;
#pragma unroll
    for (int d = 0; d < 6; ++d) {
        float s6 = ldin(sft, (size_t)b*6*M_ + d*M_ + m, f32);   // wave-uniform
        sc = fmaf(wsc[d], s6, sc); sh = fmaf(wsh[d], s6, sh);
    }
    float mod = fmaf(g, sc + 1.f, sh);
    float k = W[O_KB + lane];
#pragma unroll
    for (int i = 0; i < 64; ++i) {
        k = fmaf(W[O_T_KW + i*64 + lane], __shfl(mod, i, 64), k);
    }
    Kt[(size_t)p*64 + lane] = __float2bfloat16(k);
    Vt[(size_t)p*64 + lane] = __float2bfloat16(ldin(val, (size_t)b*64*M_ + (size_t)lane*M_ + m, f32));
}

// lexicographic (d, i) compare-exchange: keep smaller at position a
#define CE(da, ia, db, ib) { \
    bool sw_ = (db < da) || (db == da && ib < ia); \
    float td_ = da; int ti_ = ia; \
    da = sw_ ? db : da; ia = sw_ ? ib : ia; \
    db = sw_ ? td_ : db; ib = sw_ ? ti_ : ib; }

// insert (d2, m) into the sorted-16 list if it beats the tail (lex order) [proven R10]
__device__ __forceinline__ void topk_insert(float (&bd)[16], int (&bi)[16], float d2, int m) {
    if (d2 < bd[15] || (d2 == bd[15] && m < bi[15])) {
        bd[15] = d2; bi[15] = m;
#pragma unroll
        for (int j = 15; j > 0; --j) CE(bd[j-1], bi[j-1], bd[j], bi[j]);
    }
}

// lex (d2, idx) compare of LDS entry e against (cd, ci)
__device__ __forceinline__ int lesslex(uint2 e, float cd, int ci) {
    float dj = __uint_as_float(e.x);
    int   ij = (int)e.y;
    return (dj < cd || (dj == cd && ij < ci)) ? 1 : 0;
}

// ---------------- hr + kNN + attn fused (R30) ----------------
// R29 post-mortem: keeping qc in a REGISTER across the knn block detonated
// the allocator (WRITE_SIZE 1KB -> 976MB of HBM-bound scratch; 641us).
// R28 worked because the only knn->attn state was skidx in LDS (zero extra
// registers live across knn). R30: same hr prologue, but qc is parked in
// LDS (sq[256], 1KB) across selection -> live-across-knn register set is
// IDENTICAL to R28 (x,y,z,hn,L were already live there). Still deletes the
// 4MB Q round-trip + bf16 rounding + the separate hr launch.
// Pre-committed: fused >= 215us or WRITE_SIZE MB-scale -> revert to exact R28.
__global__ __launch_bounds__(256, 4) void hrknnattn_kernel(
    const void* __restrict__ xyz_hr,
    const float4* __restrict__ LR,
    const f32x4* __restrict__ PA1, const f32x4* __restrict__ PA2,
    const float* __restrict__ W,
    const __hip_bfloat16* __restrict__ Kt,
    const __hip_bfloat16* __restrict__ Vt,
    void* __restrict__ out, const int* dflag)
{
    __shared__ uint2 scand[4 * TMAX];       // 8 KiB: per-wave compacted (d2 bits, idx)
    __shared__ unsigned short skidx[4*16];  // per-wave top-16 (replaces global kidx)
    __shared__ float sq[256];               // 1 KiB: qc parked across knn (kills R29 spill)
    const int f32 = *dflag;
    int lane = threadIdx.x & 63;
    int wid  = threadIdx.x >> 6;
    int p = blockIdx.x * 4 + wid;                    // 0..32767, one point per wave
    int b = p >> 14, n = p & (N_ - 1);               // b is block-uniform
    size_t base = (size_t)b*3*N_ + n;
    float x = ldin(xyz_hr, base, f32), y = ldin(xyz_hr, base + N_, f32), z = ldin(xyz_hr, base + 2*N_, f32);
    float hn = norm3np(x, y, z);
    const float4* L = LR + b*M_;

    // ---------- hr prologue: geom enc -> qc (parked in LDS), bdy head ----------
    {
        const float* w1 = W + O_GE_W1 + lane*3;
        float h = fmaxf(fmaf(w1[2], z, fmaf(w1[1], y, fmaf(w1[0], x, W[O_GE_B1 + lane]))), 0.f);
        float g = W[O_GE_B2 + lane];
#pragma unroll
        for (int i = 0; i < 64; ++i) {
            g = fmaf(W[O_T_GE_W2 + i*64 + lane], __shfl(h, i, 64), g);
        }
        float q = W[O_QB + lane];
#pragma unroll
        for (int i = 0; i < 64; ++i) {
            q = fmaf(W[O_T_QW + i*64 + lane], __shfl(g, i, 64), q);
        }
        sq[threadIdx.x] = q;                        // park in LDS; f32, no bf16 round
        float hb = W[O_BDB1 + lane];
#pragma unroll
        for (int i = 0; i < 64; ++i) {
            hb = fmaf(W[O_T_BDW1 + i*64 + lane], __shfl(g, i, 64), hb);
        }
        float o = W[O_BDW2 + lane] * fmaxf(hb, 0.f);
#pragma unroll
        for (int sh = 1; sh < 64; sh <<= 1) o += __shfl_xor(o, sh, 64);
        if (lane == 0) {
            o += W[O_BDB2];
            stout(out, (size_t)B_*64*N_ + (size_t)b*N_ + n, 1.f / (1.f + __expf(-o)), f32);
        }
    }

    { // ---------- knn selection (R25 verbatim; exact-FP scope) ----------
#pragma clang fp reassociate(off)
#pragma clang fp contract(off)
    const f32x4* P1 = PA1 + (size_t)b*2048;
    const f32x4* P2 = PA2 + (size_t)b*2048;

    f32x2 d2p[32];
    f32x2 xx = {x, x}, yy = {y, y}, zz = {z, z}, hh = {hn, hn};
    const f32x2 m2 = {-2.f, -2.f};
    const f32x2 inf2 = {3.4e38f, 3.4e38f};
    f32x2 vm0 = inf2, vm1 = inf2;                    // tree-min accums
#pragma unroll
    for (int c = 0; c < 16; ++c) {
        int k0 = lane + (2*c + 0)*64;
        int k1 = lane + (2*c + 1)*64;
        f32x4 a0 = P1[k0];
        f32x4 b0 = P2[k0];
        f32x4 a1 = P1[k1];
        f32x4 b1 = P2[k1];
        {
            f32x2 qx = __builtin_shufflevector(a0, a0, 0, 1);
            f32x2 qy = __builtin_shufflevector(a0, a0, 2, 3);
            f32x2 qz = __builtin_shufflevector(b0, b0, 0, 1);
            f32x2 qw = __builtin_shufflevector(b0, b0, 2, 3);
            f32x2 dot = ((xx*qx) + (yy*qy)) + (zz*qz);
            f32x2 d2  = __builtin_elementwise_fma(m2, dot, hh + qw);
            d2p[2*c + 0] = d2;
            vm0 = __builtin_elementwise_min(vm0, d2);
        }
        {
            f32x2 qx = __builtin_shufflevector(a1, a1, 0, 1);
            f32x2 qy = __builtin_shufflevector(a1, a1, 2, 3);
            f32x2 qz = __builtin_shufflevector(b1, b1, 0, 1);
            f32x2 qw = __builtin_shufflevector(b1, b1, 2, 3);
            f32x2 dot = ((xx*qx) + (yy*qy)) + (zz*qz);
            f32x2 d2  = __builtin_elementwise_fma(m2, dot, hh + qw);
            d2p[2*c + 1] = d2;
            vm1 = __builtin_elementwise_min(vm1, d2);
        }
    }
    f32x2 vm = __builtin_elementwise_min(vm0, vm1);
    float v = fminf(vm.x, vm.y);
    v = fminf(v, __shfl_xor(v, 16, 64));
    v = fminf(v, __shfl_xor(v, 32, 64));
    float tau = v;
#pragma unroll
    for (int st = 1; st <= 8; st <<= 1) tau = fmaxf(tau, __shfl_xor(tau, st, 64));

    int cnt = 0;
#pragma unroll
    for (int j = 0; j < 32; ++j)
        cnt += ((d2p[j].x <= tau) ? 1 : 0) + ((d2p[j].y <= tau) ? 1 : 0);
    int inc = cnt;
#pragma unroll
    for (int st = 1; st < 64; st <<= 1) {
        int o = __shfl_up(inc, st, 64);
        if (lane >= st) inc += o;
    }
    int off = inc - cnt;                 // exclusive prefix = my write base
    int T = __shfl(inc, 63, 64);         // wave total

    if (T > TMAX) {
        // fallback: full lex top-16 scan (never expected; safety net)
        float bd[16]; int bi[16];
#pragma unroll
        for (int j = 0; j < 16; ++j) { bd[j] = 3.4e38f; bi[j] = 0x7fffffff; }
        for (int m = 0; m < M_; ++m) {
            topk_insert(bd, bi, d2np(x, y, z, hn, L[m]), m);
        }
        if (lane == 0) {
#pragma unroll
            for (int j = 0; j < 16; ++j) skidx[wid*16 + j] = (unsigned short)bi[j];
        }
    } else {
        uint2* wc = scand + wid * TMAX;
#pragma unroll
        for (int j = 0; j < 32; ++j) {
            int m0 = 2*lane + 128*j;
            if (d2p[j].x <= tau) { wc[off] = make_uint2(__float_as_uint(d2p[j].x), (unsigned)m0);     off++; }
            if (d2p[j].y <= tau) { wc[off] = make_uint2(__float_as_uint(d2p[j].y), (unsigned)(m0+1)); off++; }
        }
        int Tp = (T + 3) & ~3;
        if (lane < Tp - T) wc[T + lane] = make_uint2(0x7f800000u, 0xffffu);
        asm volatile("s_waitcnt lgkmcnt(0)" ::: "memory");

        for (int t2 = lane; t2 < T; t2 += 64) {        // T<=64 in practice: 1 iter
            uint2 cv = wc[t2];
            float cd = __uint_as_float(cv.x);
            int   ci = (int)cv.y;
            int rank = 0;
            for (int j = 0; j < Tp; j += 4) {          // wave-uniform j -> broadcast
                uint2 e0 = wc[j], e1 = wc[j+1], e2 = wc[j+2], e3 = wc[j+3];
                rank += lesslex(e0, cd, ci) + lesslex(e1, cd, ci)
                      + lesslex(e2, cd, ci) + lesslex(e3, cd, ci);
            }
            if (rank < 16) skidx[wid*16 + rank] = (unsigned short)ci;
        }
    }
    } // ---------- end knn selection ----------
    // same-wave LDS writes -> visible after waitcnt (no cross-wave sharing)
    asm volatile("s_waitcnt lgkmcnt(0)" ::: "memory");

    // ---------- attn phase (R17 body; qc reloaded from LDS, kidx from LDS) ----------
    float qc = sq[threadIdx.x];
    float fw0 = W[O_RPW1 + lane*3], fw1 = W[O_RPW1 + lane*3 + 1], fw2 = W[O_RPW1 + lane*3 + 2];
    float fb  = W[O_RPB1 + lane];
    float q2 = 0.f;
#pragma unroll
    for (int cc = 0; cc < 64; ++cc) {
        float qb = __shfl(qc, cc, 64);
        q2 = fmaf(W[O_RPW2 + cc*64 + lane], qb, q2);
    }
    int idxv = (int)skidx[wid*16 + (lane & 15)];
    const __hip_bfloat16* Ktb = Kt + (size_t)b*M_*64;
    const __hip_bfloat16* Vtb = Vt + (size_t)b*M_*64;
    float lg[16];
#pragma unroll
    for (int j = 0; j < 16; ++j) {
        int mj = __shfl(idxv, j, 64);
        mj = (mj < M_) ? mj : (M_ - 1);
        float4 pl = L[mj];
        float r0 = x - pl.x, r1 = y - pl.y, r2 = z - pl.z;
        float pe = fmaxf(fmaf(fw2, r2, fmaf(fw1, r1, fmaf(fw0, r0, fb))), 0.f);
        float vv = fmaf(qc, b2f(Ktb[(size_t)mj*64 + lane]), q2 * pe);
#pragma unroll
        for (int sh = 1; sh < 64; sh <<= 1) vv += __shfl_xor(vv, sh, 64);
        lg[j] = vv * 0.125f;
    }
    float mx = lg[0];
#pragma unroll
    for (int j = 1; j < 16; ++j) mx = fmaxf(mx, lg[j]);
    float sum = 0.f;
#pragma unroll
    for (int j = 0; j < 16; ++j) { lg[j] = __expf(lg[j] - mx); sum += lg[j]; }
    float inv = 1.f / sum;
    float o = 0.f;
#pragma unroll
    for (int j = 0; j < 16; ++j) {
        int mj = __shfl(idxv, j, 64);
        mj = (mj < M_) ? mj : (M_ - 1);
        o = fmaf(lg[j] * inv, b2f(Vtb[(size_t)mj*64 + lane]), o);
    }
    stout(out, ((size_t)(b*64 + lane))*N_ + n, o, f32);
}

// ---------------- launch ----------------
extern "C" void kernel_launch(void* const* d_in, const int* in_sizes, int n_in,
                              void* d_out, int out_size, void* d_ws, size_t ws_size,
                              hipStream_t stream) {
    const void* xyz_hr = d_in[0];
    const void* xyz_lr = d_in[1];
    const void* sft    = d_in[2];
    const void* val    = d_in[3];

    char* ws = (char*)d_ws;
    float* W  = (float*)ws;
    float4* LR = (float4*)(ws + OB_LR);
    __hip_bfloat16* Kt = (__hip_bfloat16*)(ws + OB_KT);
    __hip_bfloat16* Vt = (__hip_bfloat16*)(ws + OB_VT);
    float* PA1 = (float*)(ws + OB_PA1);
    float* PA2 = (float*)(ws + OB_PA2);
    int* dflag = (int*)(ws + OB_DFLAG);

    prep_kernel<<<16, 256, 0, stream>>>(
        xyz_hr,
        d_in[4],  d_in[5],  d_in[6],  d_in[7],  d_in[8],  d_in[9],  d_in[10], d_in[11],
        d_in[12], d_in[13], d_in[14], d_in[15], d_in[16], d_in[17], d_in[18], d_in[19],
        d_in[20], d_in[21], d_in[22], d_in[23], d_in[24], d_in[25], d_in[26], d_in[27],
        d_in[28], d_in[29], d_in[30], d_in[31], d_in[32], d_in[33], d_in[34], d_in[35],
        W, dflag);
    lr_kernel<<<2048, 256, 0, stream>>>(xyz_lr, sft, val, W, Kt, Vt, LR, PA1, PA2, dflag);
    hrknnattn_kernel<<<8192, 256, 0, stream>>>(xyz_hr, LR, (const f32x4*)PA1, (const f32x4*)PA2,
                                               W, Kt, Vt, d_out, dflag);
}